// Round 1
// baseline (12697.270 us; speedup 1.0000x reference)
//
#include <hip/hip_runtime.h>

#define TSEQ 2048
#define DM   1024
#define NBLK 4
#define NHEAD 16
#define HDIM 64
#define DFF  4096
#define NVOC 32000

// Activation scratch in device globals: immune to unknown ws_size; fully
// rewritten every call (no cross-call state dependence).
__device__ float g_h [TSEQ * DM];
__device__ float g_xn[TSEQ * DM];
__device__ float g_q [TSEQ * DM];
__device__ float g_k [TSEQ * DM];
__device__ float g_v [TSEQ * DM];
__device__ float g_ff[TSEQ * DFF];

// ---------------- embedding ----------------
__global__ __launch_bounds__(256) void embed_kernel(const int* __restrict__ x,
                                                    const float* __restrict__ tok,
                                                    const float* __restrict__ pos) {
  int t = blockIdx.x;
  const float* trow = tok + (long)x[t] * DM;
  const float* prow = pos + (long)t * DM;
  float* hrow = g_h + (long)t * DM;
  for (int i = threadIdx.x; i < DM; i += 256)
    hrow[i] = trow[i] + prow[i];
}

// ---------------- layernorm: g_h -> g_xn ----------------
__global__ __launch_bounds__(256) void ln_kernel(const float* __restrict__ gamma,
                                                 const float* __restrict__ beta) {
  int t = blockIdx.x;
  const float* xr = g_h + (long)t * DM;
  float* outr = g_xn + (long)t * DM;
  float s = 0.f, ss = 0.f;
  for (int i = threadIdx.x; i < DM; i += 256) {
    float v = xr[i];
    s += v; ss += v * v;
  }
#pragma unroll
  for (int off = 32; off; off >>= 1) {
    s  += __shfl_down(s, off);
    ss += __shfl_down(ss, off);
  }
  __shared__ float red[2][4];
  int w = threadIdx.x >> 6;
  if ((threadIdx.x & 63) == 0) { red[0][w] = s; red[1][w] = ss; }
  __syncthreads();
  s  = red[0][0] + red[0][1] + red[0][2] + red[0][3];
  ss = red[1][0] + red[1][1] + red[1][2] + red[1][3];
  float mean = s * (1.f / DM);
  float var  = ss * (1.f / DM) - mean * mean;
  float rstd = rsqrtf(var + 1e-5f);
  for (int i = threadIdx.x; i < DM; i += 256)
    outr[i] = (xr[i] - mean) * rstd * gamma[i] + beta[i];
}

// ---------------- generic f32 GEMM ----------------
// C[M,N] = act(A[M,K] @ W + bias) (+ C residual)
// W addressing: element (k, n) at W[(n>>6)*sH + k*sD + (n&63)]
//   row-major [K,N]:       sD = N,    sH = 64
//   QKV layout [H,D,HD]:   sD = HDIM, sH = DM*HDIM
// Tile 64x64, BK=16, 256 threads, 4x4 micro-tile per thread.
#define BUF_XN 0
#define BUF_FF 1
#define BUF_Q  2
#define BUF_K  3
#define BUF_V  4
#define BUF_H  5
#define BUF_OUT 6

__device__ __forceinline__ float* selbuf(int s, float* dout) {
  switch (s) {
    case 0: return g_xn;
    case 1: return g_ff;
    case 2: return g_q;
    case 3: return g_k;
    case 4: return g_v;
    case 5: return g_h;
    default: return dout;
  }
}

__global__ __launch_bounds__(256) void gemm_kernel(
    int selA, int selC, float* dout,
    const float* __restrict__ W, const float* __restrict__ bias,
    int N, int K, long sD, long sH, int relu, int resid) {
  const float* A = selbuf(selA, dout);
  float* C = selbuf(selC, dout);
  __shared__ float As[16][64];  // [k][m]
  __shared__ float Bs[16][64];  // [k][n]
  int tid = threadIdx.x;
  int n0 = blockIdx.x * 64;
  int m0 = blockIdx.y * 64;
  int tn = (tid & 15) * 4;
  int tm = (tid >> 4) * 4;
  int la_m = tid >> 2;
  int la_k = (tid & 3) * 4;
  int lb_k = tid >> 4;
  int lb_n = (tid & 15) * 4;
  const float* wbase = W + (long)(n0 >> 6) * sH;
  float acc[4][4] = {};
  for (int k0 = 0; k0 < K; k0 += 16) {
    float4 av = *(const float4*)(A + (long)(m0 + la_m) * K + k0 + la_k);
    float4 bv = *(const float4*)(wbase + (long)(k0 + lb_k) * sD + lb_n);
    __syncthreads();
    As[la_k + 0][la_m] = av.x;
    As[la_k + 1][la_m] = av.y;
    As[la_k + 2][la_m] = av.z;
    As[la_k + 3][la_m] = av.w;
    *(float4*)&Bs[lb_k][lb_n] = bv;
    __syncthreads();
#pragma unroll
    for (int kk = 0; kk < 16; ++kk) {
      float4 a = *(const float4*)&As[kk][tm];
      float4 b = *(const float4*)&Bs[kk][tn];
      acc[0][0] += a.x * b.x; acc[0][1] += a.x * b.y; acc[0][2] += a.x * b.z; acc[0][3] += a.x * b.w;
      acc[1][0] += a.y * b.x; acc[1][1] += a.y * b.y; acc[1][2] += a.y * b.z; acc[1][3] += a.y * b.w;
      acc[2][0] += a.z * b.x; acc[2][1] += a.z * b.y; acc[2][2] += a.z * b.z; acc[2][3] += a.z * b.w;
      acc[3][0] += a.w * b.x; acc[3][1] += a.w * b.y; acc[3][2] += a.w * b.z; acc[3][3] += a.w * b.w;
    }
  }
#pragma unroll
  for (int i = 0; i < 4; ++i) {
    long base = (long)(m0 + tm + i) * N + n0 + tn;
    float4 c;
    c.x = acc[i][0] + bias[n0 + tn + 0];
    c.y = acc[i][1] + bias[n0 + tn + 1];
    c.z = acc[i][2] + bias[n0 + tn + 2];
    c.w = acc[i][3] + bias[n0 + tn + 3];
    if (relu) {
      c.x = fmaxf(c.x, 0.f); c.y = fmaxf(c.y, 0.f);
      c.z = fmaxf(c.z, 0.f); c.w = fmaxf(c.w, 0.f);
    }
    if (resid) {
      float4 r = *(const float4*)(C + base);
      c.x += r.x; c.y += r.y; c.z += r.z; c.w += r.w;
    }
    *(float4*)(C + base) = c;
  }
}

// ---------------- flash attention (f32, online softmax) ----------------
// Block: 256 thr = 4 waves; block = (q-rows t0..t0+3, head). Wave w owns row
// t0+w; lane = one of 64 head dims for O, one of 64 s-values for scores.
// h[t, head*64+d] += attn  (heads write disjoint columns -> race-free)
__global__ __launch_bounds__(256) void attn_kernel() {
  __shared__ float kb[64 * 64];
  __shared__ float vb[64 * 64];
  __shared__ float qb[4][64];
  int head = blockIdx.y;
  int t0 = blockIdx.x * 4;
  int tid = threadIdx.x;
  int w = tid >> 6, lane = tid & 63;
  int t = t0 + w;
  qb[w][lane] = g_q[(long)t * DM + head * HDIM + lane];
  const float NEG = -1e30f;
  const float scale = 0.03125f;  // 1/sqrt(D) = 1/32
  float m_run = NEG, l_run = 0.f, o = 0.f;
  int smax = t0 + 3;
  for (int s0 = 0; s0 <= smax; s0 += 64) {
    __syncthreads();
#pragma unroll
    for (int i = 0; i < 16; ++i) {
      int e = tid + i * 256;
      int r = e >> 6, c = e & 63;
      int srow = s0 + r; if (srow > TSEQ - 1) srow = TSEQ - 1;
      kb[e] = g_k[(long)srow * DM + head * HDIM + c];
      vb[e] = g_v[(long)srow * DM + head * HDIM + c];
    }
    __syncthreads();
    int s = s0 + lane;
    float sc = NEG;
    if (s <= t) {
      float d = 0.f;
#pragma unroll
      for (int j = 0; j < 64; ++j) {
        int jj = (j + lane) & 63;           // rotate: kills 64-way LDS conflict
        d += qb[w][jj] * kb[lane * 64 + jj];
      }
      sc = d * scale;
    }
    float mx = sc;
#pragma unroll
    for (int off = 32; off; off >>= 1) mx = fmaxf(mx, __shfl_xor(mx, off));
    float m_new = fmaxf(m_run, mx);         // finite from chunk 0 onward
    float p = __expf(sc - m_new);           // masked lanes -> 0
    float alpha = __expf(m_run - m_new);
    float psum = p;
#pragma unroll
    for (int off = 32; off; off >>= 1) psum += __shfl_xor(psum, off);
    l_run = l_run * alpha + psum;
    m_run = m_new;
    o *= alpha;
#pragma unroll
    for (int s_i = 0; s_i < 64; ++s_i) {
      float ps = __shfl(p, s_i);
      o += ps * vb[s_i * 64 + lane];
    }
  }
  g_h[(long)t * DM + head * HDIM + lane] += o / l_run;
}

extern "C" void kernel_launch(void* const* d_in, const int* in_sizes, int n_in,
                              void* d_out, int out_size, void* d_ws, size_t ws_size,
                              hipStream_t stream) {
  (void)in_sizes; (void)n_in; (void)out_size; (void)d_ws; (void)ws_size;
  const int*   x    = (const int*)  d_in[0];
  const float* tok  = (const float*)d_in[1];
  const float* pos  = (const float*)d_in[2];
  const float* wq   = (const float*)d_in[3];
  const float* bq   = (const float*)d_in[4];
  const float* wk   = (const float*)d_in[5];
  const float* bk   = (const float*)d_in[6];
  const float* wv   = (const float*)d_in[7];
  const float* bv   = (const float*)d_in[8];
  const float* ln1g = (const float*)d_in[9];
  const float* ln1b = (const float*)d_in[10];
  const float* ln2g = (const float*)d_in[11];
  const float* ln2b = (const float*)d_in[12];
  const float* w1   = (const float*)d_in[13];
  const float* b1   = (const float*)d_in[14];
  const float* w2   = (const float*)d_in[15];
  const float* b2   = (const float*)d_in[16];
  const float* lnfg = (const float*)d_in[17];
  const float* lnfb = (const float*)d_in[18];
  const float* wvoc = (const float*)d_in[19];
  const float* bvoc = (const float*)d_in[20];
  float* out = (float*)d_out;

  embed_kernel<<<TSEQ, 256, 0, stream>>>(x, tok, pos);
  for (int l = 0; l < NBLK; ++l) {
    ln_kernel<<<TSEQ, 256, 0, stream>>>(ln1g + l * DM, ln1b + l * DM);
    dim3 gqkv(DM / 64, TSEQ / 64);
    long wq_off = (long)l * NHEAD * DM * HDIM;
    gemm_kernel<<<gqkv, 256, 0, stream>>>(BUF_XN, BUF_Q, out, wq + wq_off,
        bq + (long)l * NHEAD * HDIM, DM, DM, HDIM, (long)DM * HDIM, 0, 0);
    gemm_kernel<<<gqkv, 256, 0, stream>>>(BUF_XN, BUF_K, out, wk + wq_off,
        bk + (long)l * NHEAD * HDIM, DM, DM, HDIM, (long)DM * HDIM, 0, 0);
    gemm_kernel<<<gqkv, 256, 0, stream>>>(BUF_XN, BUF_V, out, wv + wq_off,
        bv + (long)l * NHEAD * HDIM, DM, DM, HDIM, (long)DM * HDIM, 0, 0);
    attn_kernel<<<dim3(TSEQ / 4, NHEAD), 256, 0, stream>>>();
    ln_kernel<<<TSEQ, 256, 0, stream>>>(ln2g + l * DM, ln2b + l * DM);
    gemm_kernel<<<dim3(DFF / 64, TSEQ / 64), 256, 0, stream>>>(BUF_XN, BUF_FF, out,
        w1 + (long)l * DM * DFF, b1 + (long)l * DFF, DFF, DM, DFF, 64, 1, 0);
    gemm_kernel<<<dim3(DM / 64, TSEQ / 64), 256, 0, stream>>>(BUF_FF, BUF_H, out,
        w2 + (long)l * DFF * DM, b2 + (long)l * DM, DM, DFF, DM, 64, 0, 1);
  }
  ln_kernel<<<TSEQ, 256, 0, stream>>>(lnfg, lnfb);
  gemm_kernel<<<dim3(NVOC / 64, TSEQ / 64), 256, 0, stream>>>(BUF_XN, BUF_OUT, out,
      wvoc, bvoc, NVOC, DM, NVOC, 64, 0, 0);
}